// Round 13
// baseline (250.749 us; speedup 1.0000x reference)
//
#include <hip/hip_runtime.h>
#include <hip/hip_bf16.h>

using bf16x8 = __attribute__((ext_vector_type(8))) short;
using bf16x4 = __attribute__((ext_vector_type(4))) short;
using f32x4  = __attribute__((ext_vector_type(4))) float;
using f32x2  = __attribute__((ext_vector_type(2))) float;

static __device__ __forceinline__ float bf2f(short s) {
  union { unsigned u; float f; } z;
  z.u = ((unsigned)(unsigned short)s) << 16;
  return z.f;
}
static __device__ __forceinline__ short f2bfs(float f) {
  union { __hip_bfloat16 h; short s; } u;
  u.h = __float2bfloat16(f);
  return u.s;
}
static __device__ __forceinline__ float frcp(float x) { return __builtin_amdgcn_rcpf(x); }
static __device__ __forceinline__ float sigm_f(float x) { return frcp(1.f + __expf(-x)); }
static __device__ __forceinline__ float tanh_f(float x) {
  return fmaf(2.f, frcp(1.f + __expf(-2.f * x)), -1.f);
}

typedef const __attribute__((address_space(1))) unsigned int* gas_u32;
typedef __attribute__((address_space(3))) unsigned int* las_u32;
#define GLOAD16(gp, lp) __builtin_amdgcn_global_load_lds( \
    (gas_u32)(const void*)(gp), (las_u32)(void*)(lp), 16, 0, 0)

// ===========================================================================
// Device bodies (byte-identical math to r12's proven kernels)
// ===========================================================================

// ---- cheb transpose tile: blk in [0,768) ----------------------------------
static __device__ void dev_transpose(int blk, int tid, char* smem,
    const float* __restrict__ cheb, __hip_bfloat16* __restrict__ chebT) {
  float (*tile)[65] = reinterpret_cast<float (*)[65]>(smem);
  int k = blk >> 8;
  int rem = blk & 255;
  int m0 = (rem >> 4) << 6;
  int n0 = (rem & 15) << 6;
  int tx = tid & 63;
  int ty = tid >> 6;
  const float* src = cheb + (size_t)k * 1024 * 1024;
  #pragma unroll
  for (int i = 0; i < 16; i++) {
    int ml = ty + i * 4;
    tile[ml][tx] = src[(size_t)(m0 + ml) * 1024 + n0 + tx];
  }
  __syncthreads();
  #pragma unroll
  for (int i = 0; i < 16; i++) {
    int nl = ty + i * 4;
    chebT[(size_t)(n0 + nl) * 3072 + k * 1024 + m0 + tx] =
        __float2bfloat16(tile[tx][nl]);
  }
}

// ---- TCN1 (1->64 gated) + w_cheb projection via MFMA: fblk in [0, nbt*4) --
static __device__ void dev_front(int fblk, int bt0, int tid, char* hls,
    const float* __restrict__ x,
    const float* __restrict__ w1, const float* __restrict__ b1,
    const float* __restrict__ w2, const float* __restrict__ b2,
    const float* __restrict__ w3, const float* __restrict__ b3,
    const float* __restrict__ wcheb, __hip_bfloat16* __restrict__ hwt) {
  const int lane = tid & 63, w = tid >> 6;
  const int r16 = lane & 15, kb = lane >> 4;
  const int btl = fblk >> 2;
  const int m0 = (fblk & 3) << 8;
  const int bt = bt0 + btl;
  const int b = bt / 22, t = bt % 22;

  const float* xp = x + (size_t)(b * 24 + t) * 1024 + m0 + tid;
  const float x0 = xp[0], x1 = xp[1024], x2 = xp[2048];
  const f32x2 x0v = {x0, x0}, x1v = {x1, x1}, x2v = {x2, x2};

  bf16x8 bw[3][2];
  #pragma unroll
  for (int kk = 0; kk < 3; kk++)
    #pragma unroll
    for (int ks = 0; ks < 2; ks++)
      #pragma unroll
      for (int jj = 0; jj < 8; jj++)
        bw[kk][ks][jj] = f2bfs(wcheb[kk * 1024 + (ks * 32 + kb * 8 + jj) * 16 + r16]);

  const int rswz = (tid & 7) << 4;
  #pragma unroll
  for (int cg = 0; cg < 8; cg++) {
    bf16x8 hv;
    #pragma unroll
    for (int j2 = 0; j2 < 4; j2++) {
      const int c2 = cg * 4 + j2;
      const int wi = 6 * c2;
      f32x2 pw = {b1[2*c2], b1[2*c2+1]};
      f32x2 qw = {b2[2*c2], b2[2*c2+1]};
      f32x2 rw = {b3[2*c2], b3[2*c2+1]};
      pw = __builtin_elementwise_fma(x0v, (f32x2){w1[wi], w1[wi+3]}, pw);
      qw = __builtin_elementwise_fma(x0v, (f32x2){w2[wi], w2[wi+3]}, qw);
      rw = __builtin_elementwise_fma(x0v, (f32x2){w3[wi], w3[wi+3]}, rw);
      pw = __builtin_elementwise_fma(x1v, (f32x2){w1[wi+1], w1[wi+4]}, pw);
      qw = __builtin_elementwise_fma(x1v, (f32x2){w2[wi+1], w2[wi+4]}, qw);
      rw = __builtin_elementwise_fma(x1v, (f32x2){w3[wi+1], w3[wi+4]}, rw);
      pw = __builtin_elementwise_fma(x2v, (f32x2){w1[wi+2], w1[wi+5]}, pw);
      qw = __builtin_elementwise_fma(x2v, (f32x2){w2[wi+2], w2[wi+5]}, qw);
      rw = __builtin_elementwise_fma(x2v, (f32x2){w3[wi+2], w3[wi+5]}, rw);
      hv[j2*2+0] = f2bfs(fmaf(pw.x, sigm_f(qw.x), tanh_f(rw.x)));
      hv[j2*2+1] = f2bfs(fmaf(pw.y, sigm_f(qw.y), tanh_f(rw.y)));
    }
    *(bf16x8*)(hls + tid * 128 + ((cg << 4) ^ rswz)) = hv;
  }
  __syncthreads();

  const char* Ab = hls + (w * 64 + r16) * 128;
  const int axor = (r16 & 7) << 4;
  f32x4 acc[4][3];
  #pragma unroll
  for (int mt = 0; mt < 4; mt++)
    #pragma unroll
    for (int kk = 0; kk < 3; kk++) acc[mt][kk] = (f32x4){0.f, 0.f, 0.f, 0.f};

  #pragma unroll
  for (int ks = 0; ks < 2; ks++) {
    #pragma unroll
    for (int mt = 0; mt < 4; mt++) {
      bf16x8 a = *(const bf16x8*)(Ab + mt * 2048 + ((((ks << 2) + kb) << 4) ^ axor));
      #pragma unroll
      for (int kk = 0; kk < 3; kk++)
        acc[mt][kk] = __builtin_amdgcn_mfma_f32_16x16x32_bf16(a, bw[kk][ks], acc[mt][kk], 0, 0, 0);
    }
  }

  __hip_bfloat16* hp = hwt + (size_t)bt * 49152 + r16 * 3072 + m0 + w * 64;
  #pragma unroll
  for (int kk = 0; kk < 3; kk++)
    #pragma unroll
    for (int mt = 0; mt < 4; mt++) {
      bf16x4 v;
      #pragma unroll
      for (int r = 0; r < 4; r++) v[r] = f2bfs(acc[mt][kk][r]);
      *(bf16x4*)(hp + kk * 1024 + mt * 16 + kb * 4) = v;
    }
}

// ---- tiled GEMM (r5 proven structure), blk in [0, nbt_gemm) ---------------
static __device__ void dev_gemm(int blk, int ngemm, int bt_base, int tid, char* smem,
    const __hip_bfloat16* __restrict__ chebT,
    const __hip_bfloat16* __restrict__ hwt,
    const float* __restrict__ b_cheb,
    __hip_bfloat16* __restrict__ sbuf) {
  const int lane = tid & 63;
  const int w = tid >> 6;

  int nt, ct;
  if ((ngemm & 31) == 0) {
    const int xcd = blk & 7;             // HW round-robins blockIdx across XCDs
    const int idx = blk >> 3;
    const int cgrp = ngemm >> 5;         // ct-group size per (xcd&3)
    nt = ((xcd >> 2) << 2) + (idx & 3);
    ct = (xcd & 3) * cgrp + (idx >> 2);
  } else {
    nt = blk & 7;
    ct = blk >> 3;
  }

  const int srow = tid >> 3;
  const int sswz = ((tid & 7) ^ (srow & 7)) << 4;
  const char* Ag = (const char*)chebT + (size_t)(nt * 128 + srow) * 6144 + sswz;
  const int btl = srow >> 4, so = srow & 15;
  const char* Bg = (const char*)hwt + (size_t)(bt_base + ct * 8 + btl) * 98304
                   + (size_t)so * 6144 + sswz;
  char* Als = smem + w * 1024;
  char* Bls = smem + 16384 + w * 1024;

  const int r16 = lane & 15;
  const int c16 = lane >> 4;
  const int wr = (w >> 1) << 6;
  const int wc = (w & 1) << 6;
  const int axor = (r16 & 7) << 4;
  const char* Abase = smem + (wr + r16) * 128;
  const char* Bbase = smem + 16384 + (wc + r16) * 128;

  f32x4 acc[4][4];
  #pragma unroll
  for (int i = 0; i < 4; i++)
    #pragma unroll
    for (int j = 0; j < 4; j++) acc[i][j] = (f32x4){0.f, 0.f, 0.f, 0.f};

  for (int kt = 0; kt < 48; kt++) {
    __syncthreads();
    const char* a = Ag + kt * 128;
    const char* b = Bg + kt * 128;
    #pragma unroll
    for (int i = 0; i < 4; i++) GLOAD16(a + i * 196608, Als + i * 4096);
    #pragma unroll
    for (int i = 0; i < 4; i++) GLOAD16(b + i * 196608, Bls + i * 4096);
    __syncthreads();
    #pragma unroll
    for (int ksub = 0; ksub < 2; ksub++) {
      const int ko = (ksub * 64 + c16 * 16) ^ axor;
      bf16x8 af[4], bfr[4];
      #pragma unroll
      for (int i = 0; i < 4; i++) af[i] = *(const bf16x8*)(Abase + i * 2048 + ko);
      #pragma unroll
      for (int j = 0; j < 4; j++) bfr[j] = *(const bf16x8*)(Bbase + j * 2048 + ko);
      #pragma unroll
      for (int i = 0; i < 4; i++)
        #pragma unroll
        for (int j = 0; j < 4; j++)
          acc[i][j] = __builtin_amdgcn_mfma_f32_16x16x32_bf16(af[i], bfr[j], acc[i][j], 0, 0, 0);
    }
  }

  float bias = b_cheb[r16];
  #pragma unroll
  for (int j = 0; j < 4; j++) {
    int gcol = ct * 128 + wc + j * 16 + r16;
    size_t bt_g = (size_t)bt_base + (gcol >> 4);
    int o = gcol & 15;
    #pragma unroll
    for (int i = 0; i < 4; i++) {
      int n0 = nt * 128 + wr + i * 16 + c16 * 4;
      __hip_bfloat16* sp = sbuf + (bt_g * 1024 + n0) * 16 + o;
      #pragma unroll
      for (int r = 0; r < 4; r++)
        sp[r * 16] = __float2bfloat16(acc[i][j][r] + bias);
    }
  }
}

// ---- TCN2 (16->16 gated) via MFMA: idx in [0,1280) ------------------------
static __device__ void dev_tcn2(int idx, int tid,
    const __hip_bfloat16* __restrict__ sbuf,
    const float* __restrict__ w1, const float* __restrict__ b1,
    const float* __restrict__ w2, const float* __restrict__ b2,
    const float* __restrict__ w3, const float* __restrict__ b3,
    __hip_bfloat16* __restrict__ h2b) {
  const int lane = tid & 63, w = tid >> 6;
  const int r16 = lane & 15, kb = lane >> 4;
  const int half = idx & 1;
  const int bt2 = idx >> 1;
  const int b = bt2 / 20, t2 = bt2 % 20;

  bf16x8 bw[3][2];
  const float* wps[3] = {w1, w2, w3};
  #pragma unroll
  for (int c = 0; c < 3; c++) {
    #pragma unroll
    for (int jj = 0; jj < 8; jj++) {
      int k = kb * 8 + jj;
      bw[c][0][jj] = f2bfs(wps[c][r16 * 48 + (k & 15) * 3 + (k >> 4)]);
      bw[c][1][jj] = (kb < 2) ? f2bfs(wps[c][r16 * 48 + (kb * 8 + jj) * 3 + 2]) : (short)0;
    }
  }
  const float bp = b1[r16], bq = b2[r16], br = b3[r16];

  const char* sb = (const char*)sbuf;
  const size_t slice = (size_t)1024 * 32;
  const int rowbase = half * 512 + w * 128;
  const char* baseA = sb + (size_t)(b * 22 + t2 + (kb >> 1)) * slice
                      + (size_t)(rowbase + r16) * 32 + (kb & 1) * 16;
  const char* baseC = sb + (size_t)(b * 22 + t2 + 2) * slice
                      + (size_t)(rowbase + r16) * 32 + (kb & 1) * 16;
  __hip_bfloat16* outp = h2b + ((size_t)bt2 * 1024 + rowbase + kb * 4) * 16 + r16;

  const f32x4 zro = {0.f, 0.f, 0.f, 0.f};
  #pragma unroll 2
  for (int i = 0; i < 8; i++) {
    bf16x8 a0 = *(const bf16x8*)(baseA + i * 512);
    bf16x8 a1{};
    if (kb < 2) a1 = *(const bf16x8*)(baseC + i * 512);
    f32x4 ap = __builtin_amdgcn_mfma_f32_16x16x32_bf16(a0, bw[0][0], zro, 0, 0, 0);
    f32x4 aq = __builtin_amdgcn_mfma_f32_16x16x32_bf16(a0, bw[1][0], zro, 0, 0, 0);
    f32x4 ar = __builtin_amdgcn_mfma_f32_16x16x32_bf16(a0, bw[2][0], zro, 0, 0, 0);
    ap = __builtin_amdgcn_mfma_f32_16x16x32_bf16(a1, bw[0][1], ap, 0, 0, 0);
    aq = __builtin_amdgcn_mfma_f32_16x16x32_bf16(a1, bw[1][1], aq, 0, 0, 0);
    ar = __builtin_amdgcn_mfma_f32_16x16x32_bf16(a1, bw[2][1], ar, 0, 0, 0);
    #pragma unroll
    for (int r = 0; r < 4; r++) {
      float h = fmaf(ap[r] + bp, sigm_f(aq[r] + bq), tanh_f(ar[r] + br));
      outp[(size_t)(i * 16 + r) * 16] = __float2bfloat16(h);
    }
  }
}

// ===========================================================================
// Kernels
// ===========================================================================
__global__ void __launch_bounds__(256) k_front(
    const float* x, const float* w1, const float* b1, const float* w2,
    const float* b2, const float* w3, const float* b3, const float* wcheb,
    __hip_bfloat16* hwt, int bt0, int ch,
    const float* cheb, __hip_bfloat16* chebT) {
  __shared__ __align__(16) char smem[32768];
  if ((int)blockIdx.x >= ch * 4)
    dev_transpose(blockIdx.x - ch * 4, threadIdx.x, smem, cheb, chebT);
  else
    dev_front(blockIdx.x, bt0, threadIdx.x, smem,
              x, w1, b1, w2, b2, w3, b3, wcheb, hwt);
}

// gemm(A) [0,ngemm) || front(B) [ngemm, ...)
__global__ void __launch_bounds__(256, 2) k_mid(
    const __hip_bfloat16* chebT, const __hip_bfloat16* hwt_c,
    const float* bch, __hip_bfloat16* sbuf, int ngemm, int gemm_base,
    const float* x, const float* w1, const float* b1, const float* w2,
    const float* b2, const float* w3, const float* b3, const float* wcheb,
    __hip_bfloat16* hwt, int front_bt0) {
  __shared__ __align__(16) char smem[32768];
  if ((int)blockIdx.x < ngemm)
    dev_gemm(blockIdx.x, ngemm, gemm_base, threadIdx.x, smem,
             chebT, hwt_c, bch, sbuf);
  else
    dev_front(blockIdx.x - ngemm, front_bt0, threadIdx.x, smem,
              x, w1, b1, w2, b2, w3, b3, wcheb, hwt);
}

// gemm(B) [0,ngemm) || tcn2(A) [ngemm, ngemm+640)
__global__ void __launch_bounds__(256, 2) k_mid2(
    const __hip_bfloat16* chebT, const __hip_bfloat16* hwt_c,
    const float* bch, __hip_bfloat16* sbuf, int ngemm, int gemm_base,
    const float* w1, const float* b1, const float* w2, const float* b2,
    const float* w3, const float* b3, __hip_bfloat16* h2b) {
  __shared__ __align__(16) char smem[32768];
  if ((int)blockIdx.x < ngemm)
    dev_gemm(blockIdx.x, ngemm, gemm_base, threadIdx.x, smem,
             chebT, hwt_c, bch, sbuf);
  else
    dev_tcn2(blockIdx.x - ngemm, threadIdx.x,
             sbuf, w1, b1, w2, b2, w3, b3, h2b);
}

__global__ void __launch_bounds__(256) k_tcn2w(
    const __hip_bfloat16* sbuf, const float* w1, const float* b1,
    const float* w2, const float* b2, const float* w3, const float* b3,
    __hip_bfloat16* h2b, int idx0) {
  dev_tcn2(blockIdx.x + idx0, threadIdx.x, sbuf, w1, b1, w2, b2, w3, b3, h2b);
}

__global__ void __launch_bounds__(256) k_stats2(
    const __hip_bfloat16* __restrict__ h2b, float* __restrict__ sums) {
  const int tid = threadIdx.x;
  const int n0 = (blockIdx.x & 7) << 7;
  const int bt2_0 = (blockIdx.x >> 3) << 3;
  const int n = n0 + (tid >> 1);
  const int half = tid & 1;
  const char* base = (const char*)h2b + ((size_t)bt2_0 * 1024 + n) * 32 + half * 16;
  float s = 0.f, s2 = 0.f;
  #pragma unroll
  for (int it = 0; it < 8; it++) {
    bf16x8 v = *(const bf16x8*)(base + (size_t)it * 32768);
    #pragma unroll
    for (int j = 0; j < 8; j++) { float f = bf2f(v[j]); s += f; s2 += f * f; }
  }
  s  += __shfl_xor(s, 1);
  s2 += __shfl_xor(s2, 1);
  if (half == 0) {
    atomicAdd(&sums[n], s);
    atomicAdd(&sums[1024 + n], s2);
  }
}

__global__ void __launch_bounds__(256) k_bnrelu(
    const __hip_bfloat16* __restrict__ h2b, const float* __restrict__ sums,
    const float* __restrict__ gamma, const float* __restrict__ beta,
    float* __restrict__ out) {
  size_t c = (size_t)blockIdx.x * 256 + threadIdx.x;
  int n = (int)((c >> 1) & 1023);
  float S = sums[n], S2 = sums[1024 + n];
  float mean = S * (1.f / 10240.f);
  float var  = S2 * (1.f / 10240.f) - mean * mean;
  float a  = gamma[n] * rsqrtf(var + 1e-5f);
  float cc = beta[n] - mean * a;
  bf16x8 v = *(const bf16x8*)((const char*)h2b + c * 16);
  float4* op = reinterpret_cast<float4*>(out + c * 8);
  float4 o0, o1;
  o0.x = fmaxf(0.f, fmaf(bf2f(v[0]), a, cc));
  o0.y = fmaxf(0.f, fmaf(bf2f(v[1]), a, cc));
  o0.z = fmaxf(0.f, fmaf(bf2f(v[2]), a, cc));
  o0.w = fmaxf(0.f, fmaf(bf2f(v[3]), a, cc));
  o1.x = fmaxf(0.f, fmaf(bf2f(v[4]), a, cc));
  o1.y = fmaxf(0.f, fmaf(bf2f(v[5]), a, cc));
  o1.z = fmaxf(0.f, fmaf(bf2f(v[6]), a, cc));
  o1.w = fmaxf(0.f, fmaf(bf2f(v[7]), a, cc));
  op[0] = o0;
  op[1] = o1;
}

// ===========================================================================
extern "C" void kernel_launch(void* const* d_in, const int* in_sizes, int n_in,
                              void* d_out, int out_size, void* d_ws, size_t ws_size,
                              hipStream_t stream) {
  const float* x     = (const float*)d_in[0];
  const float* cheb  = (const float*)d_in[1];
  const float* t1w1  = (const float*)d_in[2];
  const float* t1b1  = (const float*)d_in[3];
  const float* t1w2  = (const float*)d_in[4];
  const float* t1b2  = (const float*)d_in[5];
  const float* t1w3  = (const float*)d_in[6];
  const float* t1b3  = (const float*)d_in[7];
  const float* wch   = (const float*)d_in[8];
  const float* bch   = (const float*)d_in[9];
  const float* t2w1  = (const float*)d_in[10];
  const float* t2b1  = (const float*)d_in[11];
  const float* t2w2  = (const float*)d_in[12];
  const float* t2b2  = (const float*)d_in[13];
  const float* t2w3  = (const float*)d_in[14];
  const float* t2b3  = (const float*)d_in[15];
  const float* gam   = (const float*)d_in[16];
  const float* bet   = (const float*)d_in[17];

  char* ws = (char*)d_ws;
  __hip_bfloat16* chebT = (__hip_bfloat16*)ws;                   // 6,291,456 B
  __hip_bfloat16* sbuf  = (__hip_bfloat16*)(ws + 6291456);       // 23,068,672 B
  __hip_bfloat16* h2b   = (__hip_bfloat16*)(ws + 29360128);      // 20,971,520 B
  float*          sums  = (float*)(ws + 50331648);               // 8,192 B
  __hip_bfloat16* hwt   = (__hip_bfloat16*)(ws + 50339840);      // up to 69,206,016 B

  const size_t need_full = 50339840 + (size_t)704 * 98304;       // 119.5 MB
  hipMemsetAsync(sums, 0, 8192, stream);

  if (ws_size >= need_full) {
    // ---- 2-chunk software pipeline: front/gemm/tcn2 overlapped ----
    const int H = 352;   // chunk size (bt); A = [0,352), B = [352,704)
    // stage 1: front(A) + transpose rides along
    k_front<<<H * 4 + 768, 256, 0, stream>>>(
        x, t1w1, t1b1, t1w2, t1b2, t1w3, t1b3, wch, hwt, 0, H, cheb, chebT);
    // stage 2: gemm(A) || front(B)
    k_mid<<<H + H * 4, 256, 0, stream>>>(
        chebT, hwt, bch, sbuf, H, 0,
        x, t1w1, t1b1, t1w2, t1b2, t1w3, t1b3, wch, hwt, H);
    // stage 3: gemm(B) || tcn2(A: b<16 -> idx [0,640))
    k_mid2<<<H + 640, 256, 0, stream>>>(
        chebT, hwt, bch, sbuf, H, H,
        t2w1, t2b1, t2w2, t2b2, t2w3, t2b3, h2b);
    // stage 4: tcn2(B: idx [640,1280))
    k_tcn2w<<<640, 256, 0, stream>>>(sbuf, t2w1, t2b1, t2w2, t2b2, t2w3, t2b3,
                                     h2b, 640);
    k_stats2<<<640, 256, 0, stream>>>(h2b, sums);
    k_bnrelu<<<5120, 256, 0, stream>>>(h2b, sums, gam, bet, (float*)d_out);
  } else {
    // ---- fallback: serial chunked path (r12 behavior) ----
    size_t avail = ws_size > 50339840 ? ws_size - 50339840 : 0;
    int maxch = (int)(avail / 98304);
    maxch &= ~7;
    if (maxch > 704) maxch = 704;
    if (maxch < 8) maxch = 8;
    int first = 1;
    for (int bt0 = 0; bt0 < 704; bt0 += maxch) {
      int ch = (704 - bt0 < maxch) ? (704 - bt0) : maxch;
      int extra = first ? 768 : 0;
      k_front<<<ch * 4 + extra, 256, 0, stream>>>(
          x, t1w1, t1b1, t1w2, t1b2, t1w3, t1b3, wch, hwt - (size_t)bt0 * 49152,
          bt0, ch, cheb, chebT);
      // gemm over this chunk (simple mapping unless ch%32==0)
      k_mid<<<ch, 256, 0, stream>>>(
          chebT, hwt - (size_t)bt0 * 49152, bch, sbuf, ch, bt0,
          x, t1w1, t1b1, t1w2, t1b2, t1w3, t1b3, wch, hwt, 704 /*no front blocks*/);
      first = 0;
    }
    k_tcn2w<<<1280, 256, 0, stream>>>(sbuf, t2w1, t2b1, t2w2, t2b2, t2w3, t2b3,
                                      h2b, 0);
    k_stats2<<<640, 256, 0, stream>>>(h2b, sums);
    k_bnrelu<<<5120, 256, 0, stream>>>(h2b, sums, gam, bet, (float*)d_out);
  }
}

// Round 14
// 215.486 us; speedup vs baseline: 1.1636x; 1.1636x over previous
//
#include <hip/hip_runtime.h>
#include <hip/hip_bf16.h>

using bf16x8 = __attribute__((ext_vector_type(8))) short;
using bf16x4 = __attribute__((ext_vector_type(4))) short;
using f32x4  = __attribute__((ext_vector_type(4))) float;
using f32x2  = __attribute__((ext_vector_type(2))) float;

static __device__ __forceinline__ float bf2f(short s) {
  union { unsigned u; float f; } z;
  z.u = ((unsigned)(unsigned short)s) << 16;
  return z.f;
}
static __device__ __forceinline__ short f2bfs(float f) {
  union { __hip_bfloat16 h; short s; } u;
  u.h = __float2bfloat16(f);
  return u.s;
}
static __device__ __forceinline__ float frcp(float x) { return __builtin_amdgcn_rcpf(x); }
static __device__ __forceinline__ float sigm_f(float x) { return frcp(1.f + __expf(-x)); }
static __device__ __forceinline__ float tanh_f(float x) {
  return fmaf(2.f, frcp(1.f + __expf(-2.f * x)), -1.f);
}

typedef const __attribute__((address_space(1))) unsigned int* gas_u32;
typedef __attribute__((address_space(3))) unsigned int* las_u32;
#define GLOAD16(gp, lp) __builtin_amdgcn_global_load_lds( \
    (gas_u32)(const void*)(gp), (las_u32)(void*)(lp), 16, 0, 0)

// ---------------------------------------------------------------------------
// K_front (512 threads): blockIdx < ch*4  -> TCN1 + w_cheb proj (MFMA)
//                        blockIdx >= ch*4 -> cheb transpose tile (1st chunk)
// Conv split 2x: thread = (m_local = tid&255, ch_half = tid>>8), 32 ch each
// -> half the exp/rcp chain per thread. MFMA phase: 8 waves x 32 rows.
// ---------------------------------------------------------------------------
__global__ void __launch_bounds__(512) k_front(
    const float* __restrict__ x,
    const float* __restrict__ w1, const float* __restrict__ b1,
    const float* __restrict__ w2, const float* __restrict__ b2,
    const float* __restrict__ w3, const float* __restrict__ b3,
    const float* __restrict__ wcheb,
    __hip_bfloat16* __restrict__ hwt, int bt0, int ch,
    const float* __restrict__ cheb, __hip_bfloat16* __restrict__ chebT) {
  __shared__ __align__(16) char smem[32768];
  const int tid = threadIdx.x;

  if ((int)blockIdx.x >= ch * 4) {
    // ---- transpose path (512 threads): 64x64 tile
    float (*tile)[65] = reinterpret_cast<float (*)[65]>(smem);
    int blk = blockIdx.x - ch * 4;       // 0..767
    int k = blk >> 8;
    int rem = blk & 255;
    int m0 = (rem >> 4) << 6;
    int n0 = (rem & 15) << 6;
    int tx = tid & 63;
    int ty = tid >> 6;                   // 0..7
    const float* src = cheb + (size_t)k * 1024 * 1024;
    #pragma unroll
    for (int i = 0; i < 8; i++) {
      int ml = ty + i * 8;
      tile[ml][tx] = src[(size_t)(m0 + ml) * 1024 + n0 + tx];
    }
    __syncthreads();
    #pragma unroll
    for (int i = 0; i < 8; i++) {
      int nl = ty + i * 8;
      chebT[(size_t)(n0 + nl) * 3072 + k * 1024 + m0 + tx] =
          __float2bfloat16(tile[tx][nl]);
    }
    return;
  }

  // ---- TCN1 + projection path
  char* hls = smem;                      // [256 rows][128 B] swizzled
  const int btl = blockIdx.x >> 2;
  const int m0 = (blockIdx.x & 3) << 8;
  const int bt = bt0 + btl;
  const int b = bt / 22, t = bt % 22;

  // Phase 1: gated conv — thread covers 32 channels of one m
  {
    const int mrow = tid & 255;
    const int chh = tid >> 8;            // 0 or 1
    const float* xp = x + (size_t)(b * 24 + t) * 1024 + m0 + mrow;
    const float x0 = xp[0], x1 = xp[1024], x2 = xp[2048];
    const f32x2 x0v = {x0, x0}, x1v = {x1, x1}, x2v = {x2, x2};
    const int rswz = (mrow & 7) << 4;
    #pragma unroll
    for (int cgl = 0; cgl < 4; cgl++) {
      const int cg = chh * 4 + cgl;      // absolute 8-ch chunk 0..7
      bf16x8 hv;
      #pragma unroll
      for (int j2 = 0; j2 < 4; j2++) {
        const int c2 = cg * 4 + j2;      // channel-pair index
        const int wi = 6 * c2;
        f32x2 pw = {b1[2*c2], b1[2*c2+1]};
        f32x2 qw = {b2[2*c2], b2[2*c2+1]};
        f32x2 rw = {b3[2*c2], b3[2*c2+1]};
        pw = __builtin_elementwise_fma(x0v, (f32x2){w1[wi], w1[wi+3]}, pw);
        qw = __builtin_elementwise_fma(x0v, (f32x2){w2[wi], w2[wi+3]}, qw);
        rw = __builtin_elementwise_fma(x0v, (f32x2){w3[wi], w3[wi+3]}, rw);
        pw = __builtin_elementwise_fma(x1v, (f32x2){w1[wi+1], w1[wi+4]}, pw);
        qw = __builtin_elementwise_fma(x1v, (f32x2){w2[wi+1], w2[wi+4]}, qw);
        rw = __builtin_elementwise_fma(x1v, (f32x2){w3[wi+1], w3[wi+4]}, rw);
        pw = __builtin_elementwise_fma(x2v, (f32x2){w1[wi+2], w1[wi+5]}, pw);
        qw = __builtin_elementwise_fma(x2v, (f32x2){w2[wi+2], w2[wi+5]}, qw);
        rw = __builtin_elementwise_fma(x2v, (f32x2){w3[wi+2], w3[wi+5]}, rw);
        hv[j2*2+0] = f2bfs(fmaf(pw.x, sigm_f(qw.x), tanh_f(rw.x)));
        hv[j2*2+1] = f2bfs(fmaf(pw.y, sigm_f(qw.y), tanh_f(rw.y)));
      }
      *(bf16x8*)(hls + mrow * 128 + ((cg << 4) ^ rswz)) = hv;
    }
  }
  __syncthreads();

  // Phase 2: projection MFMA. 8 waves; wave w8 owns rows [w8*32, w8*32+32).
  const int lane = tid & 63, w8 = tid >> 6;
  const int r16 = lane & 15, kb = lane >> 4;

  // B fragments: col o = r16, k-elem c = ks*32 + kb*8 + jj; wcheb[k][c][o]
  bf16x8 bw[3][2];
  #pragma unroll
  for (int kk = 0; kk < 3; kk++)
    #pragma unroll
    for (int ks = 0; ks < 2; ks++)
      #pragma unroll
      for (int jj = 0; jj < 8; jj++)
        bw[kk][ks][jj] = f2bfs(wcheb[kk * 1024 + (ks * 32 + kb * 8 + jj) * 16 + r16]);

  const char* Ab = hls + (w8 * 32 + r16) * 128;
  const int axor = (r16 & 7) << 4;
  f32x4 acc[2][3];
  #pragma unroll
  for (int mt = 0; mt < 2; mt++)
    #pragma unroll
    for (int kk = 0; kk < 3; kk++) acc[mt][kk] = (f32x4){0.f, 0.f, 0.f, 0.f};

  #pragma unroll
  for (int ks = 0; ks < 2; ks++) {
    #pragma unroll
    for (int mt = 0; mt < 2; mt++) {
      bf16x8 a = *(const bf16x8*)(Ab + mt * 2048 + ((((ks << 2) + kb) << 4) ^ axor));
      #pragma unroll
      for (int kk = 0; kk < 3; kk++)
        acc[mt][kk] = __builtin_amdgcn_mfma_f32_16x16x32_bf16(a, bw[kk][ks], acc[mt][kk], 0, 0, 0);
    }
  }

  __hip_bfloat16* hp = hwt + (size_t)btl * 49152 + r16 * 3072 + m0 + w8 * 32;
  #pragma unroll
  for (int kk = 0; kk < 3; kk++)
    #pragma unroll
    for (int mt = 0; mt < 2; mt++) {
      bf16x4 v;
      #pragma unroll
      for (int r = 0; r < 4; r++) v[r] = f2bfs(acc[mt][kk][r]);
      *(bf16x4*)(hp + kk * 1024 + mt * 16 + kb * 4) = v;
    }
}

// ---------------------------------------------------------------------------
// K3: tiled GEMM  S[bt][n][o] = ChebT[n][km] * HWT[bt][o][km] + b_cheb[o]
//     EXACT r5 structure (proven 75.5us / 937 TF).
// ---------------------------------------------------------------------------
__global__ void __launch_bounds__(256, 2) k_gemm(
    const __hip_bfloat16* __restrict__ chebT,
    const __hip_bfloat16* __restrict__ hwt,
    const float* __restrict__ b_cheb,
    __hip_bfloat16* __restrict__ sbuf,
    int bt_base) {
  __shared__ __align__(16) char smem[32768];
  const int tid = threadIdx.x;
  const int lane = tid & 63;
  const int w = tid >> 6;

  int nt, ct;
  if (gridDim.x == 704) {
    const int xcd = blockIdx.x & 7;
    const int idx = blockIdx.x >> 3;
    nt = ((xcd >> 2) << 2) + (idx & 3);
    ct = (xcd & 3) * 22 + (idx >> 2);
  } else {
    nt = blockIdx.x & 7;
    ct = blockIdx.x >> 3;
  }

  const int srow = tid >> 3;
  const int sswz = ((tid & 7) ^ (srow & 7)) << 4;
  const char* Ag = (const char*)chebT + (size_t)(nt * 128 + srow) * 6144 + sswz;
  const int btl = srow >> 4, so = srow & 15;
  const char* Bg = (const char*)hwt + (size_t)(ct * 8 + btl) * 98304 + (size_t)so * 6144 + sswz;
  char* Als = smem + w * 1024;
  char* Bls = smem + 16384 + w * 1024;

  const int r16 = lane & 15;
  const int c16 = lane >> 4;
  const int wr = (w >> 1) << 6;
  const int wc = (w & 1) << 6;
  const int axor = (r16 & 7) << 4;
  const char* Abase = smem + (wr + r16) * 128;
  const char* Bbase = smem + 16384 + (wc + r16) * 128;

  f32x4 acc[4][4];
  #pragma unroll
  for (int i = 0; i < 4; i++)
    #pragma unroll
    for (int j = 0; j < 4; j++) acc[i][j] = (f32x4){0.f, 0.f, 0.f, 0.f};

  for (int kt = 0; kt < 48; kt++) {
    __syncthreads();
    const char* a = Ag + kt * 128;
    const char* b = Bg + kt * 128;
    #pragma unroll
    for (int i = 0; i < 4; i++) GLOAD16(a + i * 196608, Als + i * 4096);
    #pragma unroll
    for (int i = 0; i < 4; i++) GLOAD16(b + i * 196608, Bls + i * 4096);
    __syncthreads();
    #pragma unroll
    for (int ksub = 0; ksub < 2; ksub++) {
      const int ko = (ksub * 64 + c16 * 16) ^ axor;
      bf16x8 af[4], bfr[4];
      #pragma unroll
      for (int i = 0; i < 4; i++) af[i] = *(const bf16x8*)(Abase + i * 2048 + ko);
      #pragma unroll
      for (int j = 0; j < 4; j++) bfr[j] = *(const bf16x8*)(Bbase + j * 2048 + ko);
      #pragma unroll
      for (int i = 0; i < 4; i++)
        #pragma unroll
        for (int j = 0; j < 4; j++)
          acc[i][j] = __builtin_amdgcn_mfma_f32_16x16x32_bf16(af[i], bfr[j], acc[i][j], 0, 0, 0);
    }
  }

  float bias = b_cheb[r16];
  #pragma unroll
  for (int j = 0; j < 4; j++) {
    int gcol = ct * 128 + wc + j * 16 + r16;
    size_t bt_g = (size_t)bt_base + (gcol >> 4);
    int o = gcol & 15;
    #pragma unroll
    for (int i = 0; i < 4; i++) {
      int n0 = nt * 128 + wr + i * 16 + c16 * 4;
      __hip_bfloat16* sp = sbuf + (bt_g * 1024 + n0) * 16 + o;
      #pragma unroll
      for (int r = 0; r < 4; r++)
        sp[r * 16] = __float2bfloat16(acc[i][j][r] + bias);
    }
  }
}

// ---------------------------------------------------------------------------
// K4: fused TCN2 (16->16, gated) via MFMA; output bf16 to workspace.
// ---------------------------------------------------------------------------
__global__ void __launch_bounds__(256) k_tcn2(
    const __hip_bfloat16* __restrict__ sbuf,
    const float* __restrict__ w1, const float* __restrict__ b1,
    const float* __restrict__ w2, const float* __restrict__ b2,
    const float* __restrict__ w3, const float* __restrict__ b3,
    __hip_bfloat16* __restrict__ h2b) {
  const int tid = threadIdx.x;
  const int lane = tid & 63, w = tid >> 6;
  const int r16 = lane & 15, kb = lane >> 4;
  const int half = blockIdx.x & 1;
  const int bt2 = blockIdx.x >> 1;
  const int b = bt2 / 20, t2 = bt2 % 20;

  bf16x8 bw[3][2];
  const float* wps[3] = {w1, w2, w3};
  #pragma unroll
  for (int c = 0; c < 3; c++) {
    #pragma unroll
    for (int jj = 0; jj < 8; jj++) {
      int k = kb * 8 + jj;
      bw[c][0][jj] = f2bfs(wps[c][r16 * 48 + (k & 15) * 3 + (k >> 4)]);
      bw[c][1][jj] = (kb < 2) ? f2bfs(wps[c][r16 * 48 + (kb * 8 + jj) * 3 + 2]) : (short)0;
    }
  }
  const float bp = b1[r16], bq = b2[r16], br = b3[r16];

  const char* sb = (const char*)sbuf;
  const size_t slice = (size_t)1024 * 32;
  const int rowbase = half * 512 + w * 128;
  const char* baseA = sb + (size_t)(b * 22 + t2 + (kb >> 1)) * slice
                      + (size_t)(rowbase + r16) * 32 + (kb & 1) * 16;
  const char* baseC = sb + (size_t)(b * 22 + t2 + 2) * slice
                      + (size_t)(rowbase + r16) * 32 + (kb & 1) * 16;
  __hip_bfloat16* outp = h2b + ((size_t)bt2 * 1024 + rowbase + kb * 4) * 16 + r16;

  const f32x4 zro = {0.f, 0.f, 0.f, 0.f};
  #pragma unroll 2
  for (int i = 0; i < 8; i++) {
    bf16x8 a0 = *(const bf16x8*)(baseA + i * 512);
    bf16x8 a1{};
    if (kb < 2) a1 = *(const bf16x8*)(baseC + i * 512);
    f32x4 ap = __builtin_amdgcn_mfma_f32_16x16x32_bf16(a0, bw[0][0], zro, 0, 0, 0);
    f32x4 aq = __builtin_amdgcn_mfma_f32_16x16x32_bf16(a0, bw[1][0], zro, 0, 0, 0);
    f32x4 ar = __builtin_amdgcn_mfma_f32_16x16x32_bf16(a0, bw[2][0], zro, 0, 0, 0);
    ap = __builtin_amdgcn_mfma_f32_16x16x32_bf16(a1, bw[0][1], ap, 0, 0, 0);
    aq = __builtin_amdgcn_mfma_f32_16x16x32_bf16(a1, bw[1][1], aq, 0, 0, 0);
    ar = __builtin_amdgcn_mfma_f32_16x16x32_bf16(a1, bw[2][1], ar, 0, 0, 0);
    #pragma unroll
    for (int r = 0; r < 4; r++) {
      float h = fmaf(ap[r] + bp, sigm_f(aq[r] + bq), tanh_f(ar[r] + br));
      outp[(size_t)(i * 16 + r) * 16] = __float2bfloat16(h);
    }
  }
}

// ---------------------------------------------------------------------------
// K5: fused per-node BN stats + apply + ReLU (r10 proven form).
// ---------------------------------------------------------------------------
__global__ void __launch_bounds__(256) k_bnstats(
    const __hip_bfloat16* __restrict__ h2b, const float* __restrict__ gamma,
    const float* __restrict__ beta, float* __restrict__ out) {
  __shared__ __align__(16) short col[10240];     // [640 rows][16 ch]
  __shared__ float rs[4], rs2[4];
  const int n = blockIdx.x;
  const int tid = threadIdx.x;
  const int part = tid & 1;
  float s = 0.f, s2 = 0.f;
  for (int bt2 = tid >> 1; bt2 < 640; bt2 += 128) {
    bf16x8 v = *(const bf16x8*)((const char*)h2b +
        ((size_t)bt2 * 1024 + n) * 32 + part * 16);
    *(bf16x8*)((char*)col + bt2 * 32 + part * 16) = v;
    #pragma unroll
    for (int j = 0; j < 8; j++) { float f = bf2f(v[j]); s += f; s2 += f * f; }
  }
  #pragma unroll
  for (int off = 32; off; off >>= 1) { s += __shfl_down(s, off); s2 += __shfl_down(s2, off); }
  if ((tid & 63) == 0) { rs[tid >> 6] = s; rs2[tid >> 6] = s2; }
  __syncthreads();
  const float S  = rs[0] + rs[1] + rs[2] + rs[3];
  const float S2 = rs2[0] + rs2[1] + rs2[2] + rs2[3];
  const float mean = S * (1.f / 10240.f);
  const float var  = S2 * (1.f / 10240.f) - mean * mean;
  const float a = gamma[n] * rsqrtf(var + 1e-5f);
  const float c = beta[n] - mean * a;

  for (int bt2 = tid >> 1; bt2 < 640; bt2 += 128) {
    bf16x8 v = *(const bf16x8*)((const char*)col + bt2 * 32 + part * 16);
    float4* op = reinterpret_cast<float4*>(out + ((size_t)bt2 * 1024 + n) * 16 + part * 8);
    float4 o0, o1;
    o0.x = fmaxf(0.f, fmaf(bf2f(v[0]), a, c));
    o0.y = fmaxf(0.f, fmaf(bf2f(v[1]), a, c));
    o0.z = fmaxf(0.f, fmaf(bf2f(v[2]), a, c));
    o0.w = fmaxf(0.f, fmaf(bf2f(v[3]), a, c));
    o1.x = fmaxf(0.f, fmaf(bf2f(v[4]), a, c));
    o1.y = fmaxf(0.f, fmaf(bf2f(v[5]), a, c));
    o1.z = fmaxf(0.f, fmaf(bf2f(v[6]), a, c));
    o1.w = fmaxf(0.f, fmaf(bf2f(v[7]), a, c));
    op[0] = o0;
    op[1] = o1;
  }
}

// ---------------------------------------------------------------------------
extern "C" void kernel_launch(void* const* d_in, const int* in_sizes, int n_in,
                              void* d_out, int out_size, void* d_ws, size_t ws_size,
                              hipStream_t stream) {
  const float* x     = (const float*)d_in[0];
  const float* cheb  = (const float*)d_in[1];
  const float* t1w1  = (const float*)d_in[2];
  const float* t1b1  = (const float*)d_in[3];
  const float* t1w2  = (const float*)d_in[4];
  const float* t1b2  = (const float*)d_in[5];
  const float* t1w3  = (const float*)d_in[6];
  const float* t1b3  = (const float*)d_in[7];
  const float* wch   = (const float*)d_in[8];
  const float* bch   = (const float*)d_in[9];
  const float* t2w1  = (const float*)d_in[10];
  const float* t2b1  = (const float*)d_in[11];
  const float* t2w2  = (const float*)d_in[12];
  const float* t2b2  = (const float*)d_in[13];
  const float* t2w3  = (const float*)d_in[14];
  const float* t2b3  = (const float*)d_in[15];
  const float* gam   = (const float*)d_in[16];
  const float* bet   = (const float*)d_in[17];

  char* ws = (char*)d_ws;
  __hip_bfloat16* chebT = (__hip_bfloat16*)ws;                   // 6,291,456 B
  __hip_bfloat16* sbuf  = (__hip_bfloat16*)(ws + 6291456);       // 23,068,672 B
  __hip_bfloat16* h2b   = (__hip_bfloat16*)(ws + 29360128);      // 20,971,520 B
  __hip_bfloat16* hwt   = (__hip_bfloat16*)(ws + 50331648);      // chunk buffer

  size_t avail = ws_size > 50331648 ? ws_size - 50331648 : 0;
  int maxch = (int)(avail / 98304);
  maxch &= ~7;
  if (maxch > 704) maxch = 704;
  if (maxch < 8) maxch = 8;

  int first = 1;
  for (int bt0 = 0; bt0 < 704; bt0 += maxch) {
    int ch = (704 - bt0 < maxch) ? (704 - bt0) : maxch;
    int extra = first ? 768 : 0;          // transpose tiles ride along once
    k_front<<<ch * 4 + extra, 512, 0, stream>>>(
        x, t1w1, t1b1, t1w2, t1b2, t1w3, t1b3, wch, hwt, bt0, ch, cheb, chebT);
    k_gemm<<<ch, 256, 0, stream>>>(chebT, hwt, bch, sbuf, bt0);
    first = 0;
  }

  k_tcn2<<<1280, 256, 0, stream>>>(sbuf, t2w1, t2b1, t2w2, t2b2, t2w3, t2b3, h2b);
  k_bnstats<<<1024, 256, 0, stream>>>(h2b, gam, bet, (float*)d_out);
}

// Round 15
// 168.070 us; speedup vs baseline: 1.4919x; 1.2821x over previous
//
#include <hip/hip_runtime.h>
#include <hip/hip_bf16.h>

using bf16x8 = __attribute__((ext_vector_type(8))) short;
using bf16x4 = __attribute__((ext_vector_type(4))) short;
using f32x4  = __attribute__((ext_vector_type(4))) float;
using f32x2  = __attribute__((ext_vector_type(2))) float;

static __device__ __forceinline__ float bf2f(short s) {
  union { unsigned u; float f; } z;
  z.u = ((unsigned)(unsigned short)s) << 16;
  return z.f;
}
static __device__ __forceinline__ short f2bfs(float f) {
  union { __hip_bfloat16 h; short s; } u;
  u.h = __float2bfloat16(f);
  return u.s;
}
static __device__ __forceinline__ float frcp(float x) { return __builtin_amdgcn_rcpf(x); }
static __device__ __forceinline__ float sigm_f(float x) { return frcp(1.f + __expf(-x)); }
static __device__ __forceinline__ float tanh_f(float x) {
  return fmaf(2.f, frcp(1.f + __expf(-2.f * x)), -1.f);
}

typedef const __attribute__((address_space(1))) unsigned int* gas_u32;
typedef __attribute__((address_space(3))) unsigned int* las_u32;
#define GLOAD16(gp, lp) __builtin_amdgcn_global_load_lds( \
    (gas_u32)(const void*)(gp), (las_u32)(void*)(lp), 16, 0, 0)

// ---------------------------------------------------------------------------
// K_front: blockIdx < ch*4  -> fused TCN1 (1->64, gated) + w_cheb proj (MFMA)
//          blockIdx >= ch*4 -> cheb transpose tile (first chunk only)
// ---------------------------------------------------------------------------
__global__ void __launch_bounds__(256) k_front(
    const float* __restrict__ x,
    const float* __restrict__ w1, const float* __restrict__ b1,
    const float* __restrict__ w2, const float* __restrict__ b2,
    const float* __restrict__ w3, const float* __restrict__ b3,
    const float* __restrict__ wcheb,
    __hip_bfloat16* __restrict__ hwt, int bt0, int ch,
    const float* __restrict__ cheb, __hip_bfloat16* __restrict__ chebT) {
  __shared__ __align__(16) char smem[32768];
  const int tid = threadIdx.x;

  if ((int)blockIdx.x >= ch * 4) {
    float (*tile)[65] = reinterpret_cast<float (*)[65]>(smem);
    int blk = blockIdx.x - ch * 4;       // 0..767
    int k = blk >> 8;
    int rem = blk & 255;
    int m0 = (rem >> 4) << 6;
    int n0 = (rem & 15) << 6;
    int tx = tid & 63;
    int ty = tid >> 6;
    const float* src = cheb + (size_t)k * 1024 * 1024;
    #pragma unroll
    for (int i = 0; i < 16; i++) {
      int ml = ty + i * 4;
      tile[ml][tx] = src[(size_t)(m0 + ml) * 1024 + n0 + tx];
    }
    __syncthreads();
    #pragma unroll
    for (int i = 0; i < 16; i++) {
      int nl = ty + i * 4;
      chebT[(size_t)(n0 + nl) * 3072 + k * 1024 + m0 + tx] =
          __float2bfloat16(tile[tx][nl]);
    }
    return;
  }

  char* hls = smem;                      // [256 rows][128 B] swizzled
  const int lane = tid & 63, w = tid >> 6;
  const int r16 = lane & 15, kb = lane >> 4;
  const int btl = blockIdx.x >> 2;
  const int m0 = (blockIdx.x & 3) << 8;
  const int bt = bt0 + btl;
  const int b = bt / 22, t = bt % 22;

  const float* xp = x + (size_t)(b * 24 + t) * 1024 + m0 + tid;
  const float x0 = xp[0], x1 = xp[1024], x2 = xp[2048];
  const f32x2 x0v = {x0, x0}, x1v = {x1, x1}, x2v = {x2, x2};

  bf16x8 bw[3][2];
  #pragma unroll
  for (int kk = 0; kk < 3; kk++)
    #pragma unroll
    for (int ks = 0; ks < 2; ks++)
      #pragma unroll
      for (int jj = 0; jj < 8; jj++)
        bw[kk][ks][jj] = f2bfs(wcheb[kk * 1024 + (ks * 32 + kb * 8 + jj) * 16 + r16]);

  const int rswz = (tid & 7) << 4;
  #pragma unroll
  for (int cg = 0; cg < 8; cg++) {
    bf16x8 hv;
    #pragma unroll
    for (int j2 = 0; j2 < 4; j2++) {
      const int c2 = cg * 4 + j2;
      const int wi = 6 * c2;
      f32x2 pw = {b1[2*c2], b1[2*c2+1]};
      f32x2 qw = {b2[2*c2], b2[2*c2+1]};
      f32x2 rw = {b3[2*c2], b3[2*c2+1]};
      pw = __builtin_elementwise_fma(x0v, (f32x2){w1[wi], w1[wi+3]}, pw);
      qw = __builtin_elementwise_fma(x0v, (f32x2){w2[wi], w2[wi+3]}, qw);
      rw = __builtin_elementwise_fma(x0v, (f32x2){w3[wi], w3[wi+3]}, rw);
      pw = __builtin_elementwise_fma(x1v, (f32x2){w1[wi+1], w1[wi+4]}, pw);
      qw = __builtin_elementwise_fma(x1v, (f32x2){w2[wi+1], w2[wi+4]}, qw);
      rw = __builtin_elementwise_fma(x1v, (f32x2){w3[wi+1], w3[wi+4]}, rw);
      pw = __builtin_elementwise_fma(x2v, (f32x2){w1[wi+2], w1[wi+5]}, pw);
      qw = __builtin_elementwise_fma(x2v, (f32x2){w2[wi+2], w2[wi+5]}, qw);
      rw = __builtin_elementwise_fma(x2v, (f32x2){w3[wi+2], w3[wi+5]}, rw);
      hv[j2*2+0] = f2bfs(fmaf(pw.x, sigm_f(qw.x), tanh_f(rw.x)));
      hv[j2*2+1] = f2bfs(fmaf(pw.y, sigm_f(qw.y), tanh_f(rw.y)));
    }
    *(bf16x8*)(hls + tid * 128 + ((cg << 4) ^ rswz)) = hv;
  }
  __syncthreads();

  const char* Ab = hls + (w * 64 + r16) * 128;
  const int axor = (r16 & 7) << 4;
  f32x4 acc[4][3];
  #pragma unroll
  for (int mt = 0; mt < 4; mt++)
    #pragma unroll
    for (int kk = 0; kk < 3; kk++) acc[mt][kk] = (f32x4){0.f, 0.f, 0.f, 0.f};

  #pragma unroll
  for (int ks = 0; ks < 2; ks++) {
    #pragma unroll
    for (int mt = 0; mt < 4; mt++) {
      bf16x8 a = *(const bf16x8*)(Ab + mt * 2048 + ((((ks << 2) + kb) << 4) ^ axor));
      #pragma unroll
      for (int kk = 0; kk < 3; kk++)
        acc[mt][kk] = __builtin_amdgcn_mfma_f32_16x16x32_bf16(a, bw[kk][ks], acc[mt][kk], 0, 0, 0);
    }
  }

  __hip_bfloat16* hp = hwt + (size_t)btl * 49152 + r16 * 3072 + m0 + w * 64;
  #pragma unroll
  for (int kk = 0; kk < 3; kk++)
    #pragma unroll
    for (int mt = 0; mt < 4; mt++) {
      bf16x4 v;
      #pragma unroll
      for (int r = 0; r < 4; r++) v[r] = f2bfs(acc[mt][kk][r]);
      *(bf16x4*)(hp + kk * 1024 + mt * 16 + kb * 4) = v;
    }
}

// ---------------------------------------------------------------------------
// K3: tiled GEMM  S[bt][n][o] = ChebT[n][km] * HWT[bt][o][km] + b_cheb[o]
//     EXACT r5 structure (proven 75.5us / 937 TF).
// ---------------------------------------------------------------------------
__global__ void __launch_bounds__(256, 2) k_gemm(
    const __hip_bfloat16* __restrict__ chebT,
    const __hip_bfloat16* __restrict__ hwt,
    const float* __restrict__ b_cheb,
    __hip_bfloat16* __restrict__ sbuf,
    int bt_base) {
  __shared__ __align__(16) char smem[32768];
  const int tid = threadIdx.x;
  const int lane = tid & 63;
  const int w = tid >> 6;

  int nt, ct;
  if (gridDim.x == 704) {
    const int xcd = blockIdx.x & 7;
    const int idx = blockIdx.x >> 3;
    nt = ((xcd >> 2) << 2) + (idx & 3);
    ct = (xcd & 3) * 22 + (idx >> 2);
  } else {
    nt = blockIdx.x & 7;
    ct = blockIdx.x >> 3;
  }

  const int srow = tid >> 3;
  const int sswz = ((tid & 7) ^ (srow & 7)) << 4;
  const char* Ag = (const char*)chebT + (size_t)(nt * 128 + srow) * 6144 + sswz;
  const int btl = srow >> 4, so = srow & 15;
  const char* Bg = (const char*)hwt + (size_t)(ct * 8 + btl) * 98304 + (size_t)so * 6144 + sswz;
  char* Als = smem + w * 1024;
  char* Bls = smem + 16384 + w * 1024;

  const int r16 = lane & 15;
  const int c16 = lane >> 4;
  const int wr = (w >> 1) << 6;
  const int wc = (w & 1) << 6;
  const int axor = (r16 & 7) << 4;
  const char* Abase = smem + (wr + r16) * 128;
  const char* Bbase = smem + 16384 + (wc + r16) * 128;

  f32x4 acc[4][4];
  #pragma unroll
  for (int i = 0; i < 4; i++)
    #pragma unroll
    for (int j = 0; j < 4; j++) acc[i][j] = (f32x4){0.f, 0.f, 0.f, 0.f};

  for (int kt = 0; kt < 48; kt++) {
    __syncthreads();
    const char* a = Ag + kt * 128;
    const char* b = Bg + kt * 128;
    #pragma unroll
    for (int i = 0; i < 4; i++) GLOAD16(a + i * 196608, Als + i * 4096);
    #pragma unroll
    for (int i = 0; i < 4; i++) GLOAD16(b + i * 196608, Bls + i * 4096);
    __syncthreads();
    #pragma unroll
    for (int ksub = 0; ksub < 2; ksub++) {
      const int ko = (ksub * 64 + c16 * 16) ^ axor;
      bf16x8 af[4], bfr[4];
      #pragma unroll
      for (int i = 0; i < 4; i++) af[i] = *(const bf16x8*)(Abase + i * 2048 + ko);
      #pragma unroll
      for (int j = 0; j < 4; j++) bfr[j] = *(const bf16x8*)(Bbase + j * 2048 + ko);
      #pragma unroll
      for (int i = 0; i < 4; i++)
        #pragma unroll
        for (int j = 0; j < 4; j++)
          acc[i][j] = __builtin_amdgcn_mfma_f32_16x16x32_bf16(af[i], bfr[j], acc[i][j], 0, 0, 0);
    }
  }

  float bias = b_cheb[r16];
  #pragma unroll
  for (int j = 0; j < 4; j++) {
    int gcol = ct * 128 + wc + j * 16 + r16;
    size_t bt_g = (size_t)bt_base + (gcol >> 4);
    int o = gcol & 15;
    #pragma unroll
    for (int i = 0; i < 4; i++) {
      int n0 = nt * 128 + wr + i * 16 + c16 * 4;
      __hip_bfloat16* sp = sbuf + (bt_g * 1024 + n0) * 16 + o;
      #pragma unroll
      for (int r = 0; r < 4; r++)
        sp[r * 16] = __float2bfloat16(acc[i][j][r] + bias);
    }
  }
}

// ---------------------------------------------------------------------------
// K4: fused TCN2 (16->16, gated) via MFMA; output bf16 to workspace.
// ---------------------------------------------------------------------------
__global__ void __launch_bounds__(256) k_tcn2(
    const __hip_bfloat16* __restrict__ sbuf,
    const float* __restrict__ w1, const float* __restrict__ b1,
    const float* __restrict__ w2, const float* __restrict__ b2,
    const float* __restrict__ w3, const float* __restrict__ b3,
    __hip_bfloat16* __restrict__ h2b) {
  const int tid = threadIdx.x;
  const int lane = tid & 63, w = tid >> 6;
  const int r16 = lane & 15, kb = lane >> 4;
  const int half = blockIdx.x & 1;
  const int bt2 = blockIdx.x >> 1;
  const int b = bt2 / 20, t2 = bt2 % 20;

  bf16x8 bw[3][2];
  const float* wps[3] = {w1, w2, w3};
  #pragma unroll
  for (int c = 0; c < 3; c++) {
    #pragma unroll
    for (int jj = 0; jj < 8; jj++) {
      int k = kb * 8 + jj;
      bw[c][0][jj] = f2bfs(wps[c][r16 * 48 + (k & 15) * 3 + (k >> 4)]);
      bw[c][1][jj] = (kb < 2) ? f2bfs(wps[c][r16 * 48 + (kb * 8 + jj) * 3 + 2]) : (short)0;
    }
  }
  const float bp = b1[r16], bq = b2[r16], br = b3[r16];

  const char* sb = (const char*)sbuf;
  const size_t slice = (size_t)1024 * 32;
  const int rowbase = half * 512 + w * 128;
  const char* baseA = sb + (size_t)(b * 22 + t2 + (kb >> 1)) * slice
                      + (size_t)(rowbase + r16) * 32 + (kb & 1) * 16;
  const char* baseC = sb + (size_t)(b * 22 + t2 + 2) * slice
                      + (size_t)(rowbase + r16) * 32 + (kb & 1) * 16;
  __hip_bfloat16* outp = h2b + ((size_t)bt2 * 1024 + rowbase + kb * 4) * 16 + r16;

  const f32x4 zro = {0.f, 0.f, 0.f, 0.f};
  #pragma unroll 2
  for (int i = 0; i < 8; i++) {
    bf16x8 a0 = *(const bf16x8*)(baseA + i * 512);
    bf16x8 a1{};
    if (kb < 2) a1 = *(const bf16x8*)(baseC + i * 512);
    f32x4 ap = __builtin_amdgcn_mfma_f32_16x16x32_bf16(a0, bw[0][0], zro, 0, 0, 0);
    f32x4 aq = __builtin_amdgcn_mfma_f32_16x16x32_bf16(a0, bw[1][0], zro, 0, 0, 0);
    f32x4 ar = __builtin_amdgcn_mfma_f32_16x16x32_bf16(a0, bw[2][0], zro, 0, 0, 0);
    ap = __builtin_amdgcn_mfma_f32_16x16x32_bf16(a1, bw[0][1], ap, 0, 0, 0);
    aq = __builtin_amdgcn_mfma_f32_16x16x32_bf16(a1, bw[1][1], aq, 0, 0, 0);
    ar = __builtin_amdgcn_mfma_f32_16x16x32_bf16(a1, bw[2][1], ar, 0, 0, 0);
    #pragma unroll
    for (int r = 0; r < 4; r++) {
      float h = fmaf(ap[r] + bp, sigm_f(aq[r] + bq), tanh_f(ar[r] + br));
      outp[(size_t)(i * 16 + r) * 16] = __float2bfloat16(h);
    }
  }
}

// ---------------------------------------------------------------------------
// K5: fused per-node BN stats + apply + ReLU.  Block = node n.
// ---------------------------------------------------------------------------
__global__ void __launch_bounds__(256) k_bnstats(
    const __hip_bfloat16* __restrict__ h2b, const float* __restrict__ gamma,
    const float* __restrict__ beta, float* __restrict__ out) {
  __shared__ __align__(16) short col[10240];     // [640 rows][16 ch]
  __shared__ float rs[4], rs2[4];
  const int n = blockIdx.x;
  const int tid = threadIdx.x;
  const int part = tid & 1;
  float s = 0.f, s2 = 0.f;
  for (int bt2 = tid >> 1; bt2 < 640; bt2 += 128) {
    bf16x8 v = *(const bf16x8*)((const char*)h2b +
        ((size_t)bt2 * 1024 + n) * 32 + part * 16);
    *(bf16x8*)((char*)col + bt2 * 32 + part * 16) = v;
    #pragma unroll
    for (int j = 0; j < 8; j++) { float f = bf2f(v[j]); s += f; s2 += f * f; }
  }
  #pragma unroll
  for (int off = 32; off; off >>= 1) { s += __shfl_down(s, off); s2 += __shfl_down(s2, off); }
  if ((tid & 63) == 0) { rs[tid >> 6] = s; rs2[tid >> 6] = s2; }
  __syncthreads();
  const float S  = rs[0] + rs[1] + rs[2] + rs[3];
  const float S2 = rs2[0] + rs2[1] + rs2[2] + rs2[3];
  const float mean = S * (1.f / 10240.f);
  const float var  = S2 * (1.f / 10240.f) - mean * mean;
  const float a = gamma[n] * rsqrtf(var + 1e-5f);
  const float c = beta[n] - mean * a;

  for (int bt2 = tid >> 1; bt2 < 640; bt2 += 128) {
    bf16x8 v = *(const bf16x8*)((const char*)col + bt2 * 32 + part * 16);
    float4* op = reinterpret_cast<float4*>(out + ((size_t)bt2 * 1024 + n) * 16 + part * 8);
    float4 o0, o1;
    o0.x = fmaxf(0.f, fmaf(bf2f(v[0]), a, c));
    o0.y = fmaxf(0.f, fmaf(bf2f(v[1]), a, c));
    o0.z = fmaxf(0.f, fmaf(bf2f(v[2]), a, c));
    o0.w = fmaxf(0.f, fmaf(bf2f(v[3]), a, c));
    o1.x = fmaxf(0.f, fmaf(bf2f(v[4]), a, c));
    o1.y = fmaxf(0.f, fmaf(bf2f(v[5]), a, c));
    o1.z = fmaxf(0.f, fmaf(bf2f(v[6]), a, c));
    o1.w = fmaxf(0.f, fmaf(bf2f(v[7]), a, c));
    op[0] = o0;
    op[1] = o1;
  }
}

// ---------------------------------------------------------------------------
extern "C" void kernel_launch(void* const* d_in, const int* in_sizes, int n_in,
                              void* d_out, int out_size, void* d_ws, size_t ws_size,
                              hipStream_t stream) {
  const float* x     = (const float*)d_in[0];
  const float* cheb  = (const float*)d_in[1];
  const float* t1w1  = (const float*)d_in[2];
  const float* t1b1  = (const float*)d_in[3];
  const float* t1w2  = (const float*)d_in[4];
  const float* t1b2  = (const float*)d_in[5];
  const float* t1w3  = (const float*)d_in[6];
  const float* t1b3  = (const float*)d_in[7];
  const float* wch   = (const float*)d_in[8];
  const float* bch   = (const float*)d_in[9];
  const float* t2w1  = (const float*)d_in[10];
  const float* t2b1  = (const float*)d_in[11];
  const float* t2w2  = (const float*)d_in[12];
  const float* t2b2  = (const float*)d_in[13];
  const float* t2w3  = (const float*)d_in[14];
  const float* t2b3  = (const float*)d_in[15];
  const float* gam   = (const float*)d_in[16];
  const float* bet   = (const float*)d_in[17];

  char* ws = (char*)d_ws;
  __hip_bfloat16* chebT = (__hip_bfloat16*)ws;                   // 6,291,456 B
  __hip_bfloat16* sbuf  = (__hip_bfloat16*)(ws + 6291456);       // 23,068,672 B
  __hip_bfloat16* h2b   = (__hip_bfloat16*)(ws + 29360128);      // 20,971,520 B
  __hip_bfloat16* hwt   = (__hip_bfloat16*)(ws + 50331648);      // chunk buffer

  size_t avail = ws_size > 50331648 ? ws_size - 50331648 : 0;
  int maxch = (int)(avail / 98304);
  maxch &= ~7;
  if (maxch > 704) maxch = 704;
  if (maxch < 8) maxch = 8;

  int first = 1;
  for (int bt0 = 0; bt0 < 704; bt0 += maxch) {
    int ch = (704 - bt0 < maxch) ? (704 - bt0) : maxch;
    int extra = first ? 768 : 0;          // transpose tiles ride along once
    k_front<<<ch * 4 + extra, 256, 0, stream>>>(
        x, t1w1, t1b1, t1w2, t1b2, t1w3, t1b3, wch, hwt, bt0, ch, cheb, chebT);
    k_gemm<<<ch, 256, 0, stream>>>(chebT, hwt, bch, sbuf, bt0);
    first = 0;
  }

  k_tcn2<<<1280, 256, 0, stream>>>(sbuf, t2w1, t2b1, t2w2, t2b2, t2w3, t2b3, h2b);
  k_bnstats<<<1024, 256, 0, stream>>>(h2b, gam, bet, (float*)d_out);
}